// Round 15
// baseline (1104.962 us; speedup 1.0000x reference)
//
#include <hip/hip_runtime.h>
#include <math.h>

#define T_ 64
#define M_ 256
#define K_ 6
#define B_ 256
#define H_ 256
#define L_ 128
#define V_ 780
#define E_ (T_*M_)       // 16384
#define ZD 383           // H+L-1
#define UD 638           // 2H+L-2
#define KP 384           // ZD padded for MFMA
#define VP 832           // V padded to 13*64

typedef unsigned short ushort_t;
typedef __attribute__((ext_vector_type(8))) _Float16 half8v;
typedef __attribute__((ext_vector_type(4))) _Float16 half4v;
typedef __attribute__((ext_vector_type(4))) float f32x4v;

// ---------------- helpers ----------------

__device__ __forceinline__ float blk_sum(float v, float* red) {
    int j = threadIdx.x;
    #pragma unroll
    for (int o = 32; o > 0; o >>= 1) v += __shfl_down(v, o, 64);
    __syncthreads();
    if ((j & 63) == 0) red[j >> 6] = v;
    __syncthreads();
    return red[0] + red[1] + red[2] + red[3];
}

__device__ __forceinline__ float wave_sum(float v) {
    #pragma unroll
    for (int o = 32; o > 0; o >>= 1) v += __shfl_xor(v, o, 64);
    return v;
}

__device__ __forceinline__ void wave_maxarg(float& v, int& i) {
    #pragma unroll
    for (int o = 32; o > 0; o >>= 1) {
        float vo = __shfl_xor(v, o, 64);
        int   io = __shfl_xor(i, o, 64);
        if (vo > v || (vo == v && io < i)) { v = vo; i = io; }
    }
}

__device__ __forceinline__ _Float16 f2h(float x) { return (_Float16)x; }

// LLC-coherent (agent-scope) accessors for mutable cross-step state
__device__ __forceinline__ float llc_load(const float* p) {
    return __hip_atomic_load(p, __ATOMIC_RELAXED, __HIP_MEMORY_SCOPE_AGENT);
}
__device__ __forceinline__ void llc_store(float* p, float v) {
    __hip_atomic_store(p, v, __ATOMIC_RELAXED, __HIP_MEMORY_SCOPE_AGENT);
}

// ---------------- fused prep: hbuf init (flags!) + W packs + wcls conv ----------------
// hbuf rows 0..E-1: h[0]=0 is the "not yet written" flag (written rows have
// h[0]>=1.1); these rows are NEVER read before being written (neighbor ids at
// step t are in [0,t*M) or PAD). Row E (PAD) fully = (1,0,...,0).

#define PREP_R0 ((E_ + 1) * H_)          // hbuf
#define PREP_R1 65536                    // W0P  (16*8*64*8)
#define PREP_R2 131072                   // W1P  (16*16*64*8)
#define PREP_R3 (VP * KP)                // Wh
#define PREP_TOTAL (PREP_R0 + PREP_R1 + PREP_R2 + PREP_R3)

__global__ __launch_bounds__(256) void prep_k(const float* __restrict__ W0,
                                              const float* __restrict__ W1,
                                              const float* __restrict__ wcls,
                                              float* __restrict__ hbuf,
                                              _Float16* __restrict__ W0P,
                                              _Float16* __restrict__ W1P,
                                              _Float16* __restrict__ Wh) {
    int idx = blockIdx.x * 256 + threadIdx.x;
    if (idx < PREP_R0) {
        // rows < E: all zeros (h[0]==0 is the dataflow flag). Row E: (1,0,..,0).
        hbuf[idx] = (idx >= E_ * H_ && (idx & (H_ - 1)) == 0) ? 1.f : 0.f;
        return;
    }
    idx -= PREP_R0;
    if (idx < PREP_R1) {
        // W0P[((nt*8+ks)*64+l)*8+e] = W0[(nt*16+(l&15)) * H + ks*32+(l>>4)*8+e]
        int e = idx & 7, l = (idx >> 3) & 63, ks = (idx >> 9) & 7, nt = idx >> 12;
        int jj = nt * 16 + (l & 15);
        int ii = ks * 32 + (l >> 4) * 8 + e;
        W0P[idx] = f2h(W0[(size_t)jj * H_ + ii]);
        return;
    }
    idx -= PREP_R1;
    if (idx < PREP_R2) {
        int e = idx & 7, l = (idx >> 3) & 63, ks = (idx >> 9) & 15, nt = idx >> 13;
        int jj = nt * 16 + (l & 15);
        int ii = ks * 32 + (l >> 4) * 8 + e;
        W1P[idx] = (ii < 2 * H_ - 1) ? f2h(W1[(size_t)jj * (2 * H_ - 1) + ii]) : (_Float16)0.f;
        return;
    }
    idx -= PREP_R2;
    if (idx < PREP_R3) {
        int v = idx / KP, k = idx - v * KP;
        float val = (v < V_ && k < ZD) ? wcls[(size_t)v * ZD + k] : 0.f;
        Wh[idx] = f2h(val);
    }
}

// ---------------- dataflow scan + fused Zh build, 3 barriers/step ----------------
// 256 blocks (1/CU, co-resident) x 256 threads. Block m computes row t*M+m.
// Gather = fused dep-wait + CACHEABLE float4 loads: published rows are
// immutable, and normal loads happen only post-flag, so no L2 can hold a
// pre-publication copy -> cacheable loads are safe. The load address carries
// an opaque (inline-asm) dependency on the polled flag value so neither the
// compiler nor HW can hoist it above the spin. Per-wave zz copies remove the
// B3 barrier (every wave holds the full nonlinear result across its lanes).
// Producer publishes via sc1 col stores + RELEASE flag store (rounds 12-14,
// absmax 0.0). MFMA fragment layouts identical to rounds 10-14.

__global__ __launch_bounds__(256) void scan_flow(float* __restrict__ hbuf,
        const _Float16* __restrict__ W0P, const float* __restrict__ b0, const float* __restrict__ s0p,
        const _Float16* __restrict__ W1P, const float* __restrict__ b1, const float* __restrict__ s1p,
        const float* __restrict__ emb, const int* __restrict__ wid,
        const int* __restrict__ nhi, const float* __restrict__ nhw,
        const int* __restrict__ bidx, const float* __restrict__ xtv,
        _Float16* __restrict__ Zh) {
    int tid = threadIdx.x;
    int w = tid >> 6, l = tid & 63;
    int quad = l >> 4, col = l & 15;
    int m = blockIdx.x;
    int j0 = 4 * l;

    __shared__ __align__(16) _Float16 hn16[16][264];   // rows 0..5 staged
    __shared__ __align__(16) _Float16 zz16[4][520];    // per-wave copies
    __shared__ __align__(16) float Ys[6][256];
    __shared__ __align__(16) float y2s[256];

    float es0 = expf(s0p[0]);
    float es1 = expf(s1p[0]);
    float4 bj4 = *(const float4*)(b0 + j0);
    float4 b14 = *(const float4*)(b1 + j0);

    for (int t = 0; t < T_; t++) {
        int e = t * M_ + m;
        const int*   ip = nhi + e * K_;
        const float* wp = nhw + e * K_;

        // ---- fused dep-wait + cacheable gather ----
        // task tau: row tau>>6, cols (tau&63)*4 .. +3; 384 tasks over 2 passes
        #pragma unroll
        for (int p = 0; p < 2; p++) {
            int task = tid + p * 256;
            if (task < 384) {
                int r = task >> 6, c = (task & 63) * 4;
                int id = ip[r];
                float fl = 1.f;
                if (id < E_) {
                    fl = llc_load(&hbuf[(size_t)id * H_]);
                    while (fl < 0.5f) {
                        __builtin_amdgcn_s_sleep(1);
                        fl = llc_load(&hbuf[(size_t)id * H_]);
                    }
                }
                int off = 0;
                asm volatile("" : "+v"(off) : "v"(fl));   // opaque addr dep on flag
                float4 v = *(const float4*)(hbuf + (size_t)id * H_ + c + off);
                *(half4v*)&hn16[r][c] = (half4v){f2h(v.x), f2h(v.y), f2h(v.z), f2h(v.w)};
            }
        }
        __syncthreads();                                           // B1

        // ---- W0 GEMM via MFMA: wave w -> nt 4w..4w+3, 32 MFMA/wave ----
        f32x4v acc[4];
        #pragma unroll
        for (int q = 0; q < 4; q++) acc[q] = (f32x4v){0.f, 0.f, 0.f, 0.f};
        #pragma unroll
        for (int ks = 0; ks < 8; ks++) {
            half8v afr = *(const half8v*)&hn16[col][ks * 32 + quad * 8];
            #pragma unroll
            for (int q = 0; q < 4; q++) {
                int nt = 4 * w + q;
                half8v bf = *(const half8v*)(W0P + ((size_t)(nt * 8 + ks) * 64 + l) * 8);
                acc[q] = __builtin_amdgcn_mfma_f32_16x16x32_f16(afr, bf, acc[q], 0, 0, 0);
            }
        }
        #pragma unroll
        for (int q = 0; q < 4; q++) {
            int nt = 4 * w + q;
            #pragma unroll
            for (int r = 0; r < 4; r++) {
                int row = quad * 4 + r;
                if (row < 6) Ys[row][nt * 16 + col] = acc[q][r];
            }
        }
        __syncthreads();                                           // B2

        // ---- nonlinear phase A: lane owns cols 4l..4l+3, wave-local reductions ----
        float y[K_][4];
        #pragma unroll
        for (int k = 0; k < K_; k++) {
            float4 yv = *(const float4*)&Ys[k][j0];
            y[k][0] = yv.x + bj4.x; y[k][1] = yv.y + bj4.y;
            y[k][2] = yv.z + bj4.z; y[k][3] = yv.w + bj4.w;
        }
        float ave[4] = {0.f, 0.f, 0.f, 0.f};
        float wsum = 0.f;
        #pragma unroll
        for (int k = 0; k < K_; k++) {
            float c = y[k][0] * y[k][0] + y[k][1] * y[k][1]
                    + y[k][2] * y[k][2] + y[k][3] * y[k][3];
            if (l == 0) c -= y[k][0] * y[k][0];          // exclude j==0 term
            float ssq = wave_sum(c);
            float y0k = __shfl(y[k][0], 0, 64);
            float tm  = es0 / (1.f + expf(-y0k)) + 1.1f;
            float sc  = sqrtf((tm * tm - 1.f) / fmaxf(ssq, 1e-8f));
            float wk  = wp[k];
            #pragma unroll
            for (int c2 = 0; c2 < 4; c2++) {
                float h1v = (l == 0 && c2 == 0) ? tm : y[k][c2] * sc;
                ave[c2] += wk * h1v;
            }
            wsum += wk;
        }
        float inv = 1.f / fmaxf(wsum, 1e-8f);
        float innl = 0.f;
        #pragma unroll
        for (int c2 = 0; c2 < 4; c2++) { ave[c2] *= inv; innl += ave[c2] * ave[c2]; }
        if (l == 0) innl -= 2.f * ave[0] * ave[0];       // j==0 contributes -ave0^2
        float inner = wave_sum(innl);
        float rsc = 1.f / sqrtf(fmaxf(-inner, 1e-8f));

        int wde = wid[e];
        float4 cx4 = *(const float4*)(emb + (size_t)wde * H_ + j0);
        float cx[4] = {cx4.x, cx4.y, cx4.z, cx4.w};

        // per-wave zz copy (all waves hold identical full results) -> no barrier
        #pragma unroll
        for (int c2 = 0; c2 < 4; c2++) {
            int j = j0 + c2;
            float h1m = ave[c2] * rsc;
            if (j == 0) {
                zz16[w][0] = f2h(sqrtf(fmaxf(cx[0] * cx[0] + h1m * h1m - 1.f, 1e-8f)));
            } else {
                zz16[w][j] = f2h(cx[c2]);
                zz16[w][255 + j] = f2h(h1m);
            }
        }
        if (l == 63) zz16[w][511] = (_Float16)0.f;
        // same-wave LDS write->read: lgkmcnt ordering, no __syncthreads needed

        // ---- W1 GEMV via MFMA: 64 MFMA/wave, only D row 0 used ----
        f32x4v a2[4];
        #pragma unroll
        for (int q = 0; q < 4; q++) a2[q] = (f32x4v){0.f, 0.f, 0.f, 0.f};
        #pragma unroll
        for (int ks = 0; ks < 16; ks++) {
            half8v zfr = *(const half8v*)&zz16[w][ks * 32 + quad * 8];
            #pragma unroll
            for (int q = 0; q < 4; q++) {
                int nt = 4 * w + q;
                half8v bf = *(const half8v*)(W1P + ((size_t)(nt * 16 + ks) * 64 + l) * 8);
                a2[q] = __builtin_amdgcn_mfma_f32_16x16x32_f16(zfr, bf, a2[q], 0, 0, 0);
            }
        }
        if (quad == 0) {
            #pragma unroll
            for (int q = 0; q < 4; q++) y2s[(4 * w + q) * 16 + col] = a2[q][0];
        }
        __syncthreads();                                           // B4

        // ---- tail: wave 0 finishes row + publishes + writes Zh cols 0..255;
        //      waves 1-2 write Zh ctx cols 256..383 (zbuild fused) ----
        if (w == 0) {
            float4 y2v = *(const float4*)&y2s[j0];
            float y2[4] = {y2v.x + b14.x, y2v.y + b14.y, y2v.z + b14.z, y2v.w + b14.w};
            float c2s = y2[0] * y2[0] + y2[1] * y2[1] + y2[2] * y2[2] + y2[3] * y2[3];
            if (l == 0) c2s -= y2[0] * y2[0];
            float ssq2 = wave_sum(c2s);
            float y20 = __shfl(y2[0], 0, 64);
            float tm2 = es1 / (1.f + expf(-y20)) + 1.1f;
            float sc2 = sqrtf((tm2 * tm2 - 1.f) / fmaxf(ssq2, 1e-8f));
            float nh[4];
            nh[0] = (l == 0) ? tm2 : y2[0] * sc2;
            nh[1] = y2[1] * sc2; nh[2] = y2[2] * sc2; nh[3] = y2[3] * sc2;

            // Zh row, cols j0..j0+3 (lane 0 folds -z0 into col 0)
            half4v zv;
            if (l == 0) {
                float c0 = xtv[(size_t)bidx[e] * L_];
                float z0 = sqrtf(fmaxf(tm2 * tm2 + c0 * c0 - 1.f, 1e-8f));
                zv[0] = f2h(-z0);
            } else {
                zv[0] = f2h(nh[0]);
            }
            zv[1] = f2h(nh[1]); zv[2] = f2h(nh[2]); zv[3] = f2h(nh[3]);
            *(half4v*)(Zh + (size_t)e * KP + j0) = zv;

            // hbuf cols (relaxed sc1), then lane 0 publishes flag with RELEASE
            float* hr = hbuf + (size_t)e * H_ + j0;
            llc_store(hr + 1, nh[1]);
            llc_store(hr + 2, nh[2]);
            llc_store(hr + 3, nh[3]);
            if (l != 0) llc_store(hr + 0, nh[0]);
            if (l == 0)
                __hip_atomic_store(&hbuf[(size_t)e * H_], tm2,
                                   __ATOMIC_RELEASE, __HIP_MEMORY_SCOPE_AGENT);
        } else if (w <= 2) {
            int idx = tid - 64;                 // 0..127
            if (idx < 128) {
                int bi = bidx[e];
                float v = (idx < 127) ? xtv[(size_t)bi * L_ + idx + 1] : 0.f;
                Zh[(size_t)e * KP + 256 + idx] = f2h(v);
            }
        }
        // next iteration's B1 re-converges the block (hn16 reads ended at B2)
    }
}

// ---------------- msg scores GEMM (MFMA fp16): SC = 2 + 2*(Z @ wcls^T) + wbias ----------------

__global__ __launch_bounds__(256) void gemm_mfma(const _Float16* __restrict__ Zh,
                                                 const _Float16* __restrict__ Wh,
                                                 const float* __restrict__ wbias,
                                                 float* __restrict__ SC) {
    __shared__ __align__(16) _Float16 As[64][40];
    __shared__ __align__(16) _Float16 Bs[64][40];
    int tid = threadIdx.x;
    int w = tid >> 6, l = tid & 63;
    int m0 = blockIdx.x * 64;
    int n0 = blockIdx.y * 64;
    int r16 = l & 15, q8 = (l >> 4) * 8;

    int srow = tid >> 2;            // 0..63
    int schunk = (tid & 3) * 8;     // 0,8,16,24

    f32x4v acc[4];
    #pragma unroll
    for (int mt = 0; mt < 4; mt++) acc[mt] = (f32x4v){0.f, 0.f, 0.f, 0.f};

    for (int ks = 0; ks < KP / 32; ks++) {
        int k0 = ks * 32;
        __syncthreads();
        *(uint4*)&As[srow][schunk] = *(const uint4*)(Zh + (size_t)(m0 + srow) * KP + k0 + schunk);
        *(uint4*)&Bs[srow][schunk] = *(const uint4*)(Wh + (size_t)(n0 + srow) * KP + k0 + schunk);
        __syncthreads();

        half8v bfr = *(const half8v*)(&Bs[w * 16 + r16][q8]);
        #pragma unroll
        for (int mt = 0; mt < 4; mt++) {
            half8v afr = *(const half8v*)(&As[mt * 16 + r16][q8]);
            acc[mt] = __builtin_amdgcn_mfma_f32_16x16x32_f16(afr, bfr, acc[mt], 0, 0, 0);
        }
    }

    int n = n0 + w * 16 + r16;
    if (n < V_) {
        float bias = wbias[n];
        #pragma unroll
        for (int mt = 0; mt < 4; mt++) {
            #pragma unroll
            for (int r = 0; r < 4; r++) {
                int mrow = m0 + mt * 16 + (l >> 4) * 4 + r;
                SC[(size_t)mrow * V_ + n] = 2.f + 2.f * acc[mt][r] + bias;
            }
        }
    }
}

// ---------------- msg CE (masked by direction), wave-per-row, no atomics ----------------

__global__ __launch_bounds__(256) void msg_ce2(const float* __restrict__ SC,
                                               const int* __restrict__ pt,
                                               const int* __restrict__ dir,
                                               float* __restrict__ part) {
    int w = threadIdx.x >> 6, l = threadIdx.x & 63;
    int wg = blockIdx.x * 4 + w;     // 0..1023
    float lloss = 0.f, lhit = 0.f, lpm = 0.f;
    for (int i = 0; i < 16; i++) {
        int e = wg * 16 + i;
        const float* s = SC + (size_t)e * V_;
        float sv[13];
        float mx = -1e30f; int mi = 0;
        #pragma unroll
        for (int ii = 0; ii < 13; ii++) {
            int v = l + ii * 64;
            float x = (v < V_) ? s[v] : -1e30f;
            sv[ii] = x;
            if (x > mx) { mx = x; mi = v; }
        }
        wave_maxarg(mx, mi);
        float se = 0.f;
        #pragma unroll
        for (int ii = 0; ii < 13; ii++) se += expf(sv[ii] - mx);
        se = wave_sum(se);
        if (l == 0) {
            int tgt = pt[e];
            float lse = mx + logf(se);
            float pm = (float)dir[e];
            lloss += pm * (lse - s[tgt]);
            lhit  += pm * ((mi == tgt) ? 1.f : 0.f);
            lpm   += pm;
        }
    }
    __shared__ float red[4][3];
    if (l == 0) { red[w][0] = lloss; red[w][1] = lhit; red[w][2] = lpm; }
    __syncthreads();
    if (threadIdx.x == 0) {
        float* pr = part + (size_t)blockIdx.x * 8;
        pr[0] = red[0][0] + red[1][0] + red[2][0] + red[3][0];
        pr[1] = red[0][1] + red[1][1] + red[2][1] + red[3][1];
        pr[2] = red[0][2] + red[1][2] + red[2][2] + red[3][2];
        pr[3] = 0.f; pr[4] = 0.f;
    }
}

// ---------------- fused stop head (blocks 0..255) + root (blocks 256..511) ----------------

__global__ __launch_bounds__(256) void stoproot_k(const float* __restrict__ hbuf,
        const float* __restrict__ emb, const float* __restrict__ xtv,
        const int* __restrict__ wid, const int* __restrict__ noi, const float* __restrict__ now_w,
        const int* __restrict__ bidx, const int* __restrict__ dir,
        const int* __restrict__ rwid, const int* __restrict__ roi, const float* __restrict__ row_w,
        const float* __restrict__ wcls, const float* __restrict__ wbias,
        const float* __restrict__ ucls, const float* __restrict__ ubias,
        float* __restrict__ part) {
    __shared__ float red[256];
    __shared__ int   redi[256];
    __shared__ float shs[4];
    __shared__ float ctxs[L_];
    __shared__ float sc[V_];
    __shared__ float red2[4][2];

    if (blockIdx.x < 256) {
        // ---------- stop head per message (64 e's per block, wave-per-row) ----------
        int w = threadIdx.x >> 6, l = threadIdx.x & 63;
        int wg = blockIdx.x * 4 + w;

        float ua0[4], ub0[4], ua1[4], ub1[4], uc0[2], uc1[2];
        #pragma unroll
        for (int s = 0; s < 4; s++) {
            int j = s * 64 + l;
            ua0[s] = ucls[j];        ub0[s] = ucls[255 + j];
            ua1[s] = ucls[UD + j];   ub1[s] = ucls[UD + 255 + j];
        }
        #pragma unroll
        for (int s = 0; s < 2; s++) {
            int j = s * 64 + l;
            uc0[s] = ucls[510 + j];  uc1[s] = ucls[UD + 510 + j];
        }
        float u00 = ucls[0], u10 = ucls[UD];
        float ubs0 = ubias[0], ubs1 = ubias[1];

        float lloss = 0.f, lhit = 0.f;
        for (int i = 0; i < 16; i++) {
            int e = wg * 16 + i;
            const int*   ip = noi + e * K_;
            const float* wp = now_w + e * K_;
            float ave[4] = {0.f, 0.f, 0.f, 0.f};
            float wsum = 0.f;
            #pragma unroll
            for (int k = 0; k < K_; k++) {
                int id = ip[k]; float wt = wp[k];
                wsum += wt;
                const float* hr = hbuf + (size_t)id * H_;
                #pragma unroll
                for (int s = 0; s < 4; s++) ave[s] += wt * hr[s * 64 + l];
            }
            float inv = 1.f / fmaxf(wsum, 1e-8f);
            float innl = 0.f;
            #pragma unroll
            for (int s = 0; s < 4; s++) { ave[s] *= inv; innl += ave[s] * ave[s]; }
            if (l == 0) innl -= 2.f * ave[0] * ave[0];
            float inner = wave_sum(innl);
            float cs = 1.f / sqrtf(fmaxf(-inner, 1e-8f));

            int we = wid[e], bi = bidx[e];
            const float* er = emb + (size_t)we * H_;
            const float* cr = xtv + (size_t)bi * L_;

            float p0 = 0.f, p1 = 0.f;
            #pragma unroll
            for (int s = 0; s < 4; s++) {
                float cx = er[s * 64 + l];
                float co = ave[s] * cs;
                if (s == 0 && l == 0) {
                    float ctx0 = cr[0];
                    float t1sq = fmaxf(cx * cx + co * co - 1.f, 1e-8f);
                    float sh0 = sqrtf(fmaxf(t1sq + ctx0 * ctx0 - 1.f, 1e-8f));
                    p0 += -sh0 * u00; p1 += -sh0 * u10;
                } else {
                    p0 += cx * ua0[s] + co * ub0[s];
                    p1 += cx * ua1[s] + co * ub1[s];
                }
                if (s < 2) {
                    int j = s * 64 + l;
                    if (j >= 1) {
                        float ctx = cr[j];
                        p0 += ctx * uc0[s]; p1 += ctx * uc1[s];
                    }
                }
            }
            p0 = wave_sum(p0); p1 = wave_sum(p1);
            if (l == 0) {
                float sc0 = 2.f + 2.f * p0 + ubs0;
                float sc1 = 2.f + 2.f * p1 + ubs1;
                int tgt = dir[e];
                float mm = fmaxf(sc0, sc1);
                float lse = mm + logf(expf(sc0 - mm) + expf(sc1 - mm));
                lloss += lse - ((tgt == 0) ? sc0 : sc1);
                int am = (sc1 > sc0) ? 1 : 0;
                lhit += (am == tgt) ? 1.f : 0.f;
            }
        }
        if (l == 0) { red2[w][0] = lloss; red2[w][1] = lhit; }
        __syncthreads();
        if (threadIdx.x == 0) {
            float* pr = part + (size_t)(256 + blockIdx.x) * 8;
            pr[0] = 0.f; pr[1] = 0.f; pr[2] = 0.f;
            pr[3] = red2[0][0] + red2[1][0] + red2[2][0] + red2[3][0];
            pr[4] = red2[0][1] + red2[1][1] + red2[2][1] + red2[3][1];
        }
    } else {
        // ---------- root: stop head + pred head ----------
        int b = blockIdx.x - 256, j = threadIdx.x;
        float* pr = part + (size_t)(512 + b) * 8;

        const int*   ip = roi + b * K_;
        const float* wp = row_w + b * K_;
        float ave = 0.f, wsum = 0.f;
        #pragma unroll
        for (int k = 0; k < K_; k++) {
            int id = ip[k]; float w = wp[k];
            ave += w * hbuf[(size_t)id * H_ + j];
            wsum += w;
        }
        ave /= fmaxf(wsum, 1e-8f);
        float inner = blk_sum((j == 0) ? -ave * ave : ave * ave, red);
        float ro = ave / sqrtf(fmaxf(-inner, 1e-8f));

        int   rw = rwid[b];
        float er = emb[(size_t)rw * H_ + j];
        float ctxj = (j < L_) ? xtv[(size_t)b * L_ + j] : 0.f;
        if (j == 0) { shs[0] = er; shs[1] = ro; shs[2] = ctxj; }
        if (j < L_) ctxs[j] = ctxj;
        __syncthreads();
        float t1sq = fmaxf(shs[0] * shs[0] + shs[1] * shs[1] - 1.f, 1e-8f);
        float sh0  = sqrtf(fmaxf(t1sq + shs[2] * shs[2] - 1.f, 1e-8f));

        float p0, p1;
        if (j >= 1) {
            p0 = er * ucls[j] + ro * ucls[255 + j];
            p1 = er * ucls[UD + j] + ro * ucls[UD + 255 + j];
            if (j < L_) { p0 += ctxj * ucls[510 + j]; p1 += ctxj * ucls[UD + 510 + j]; }
        } else {
            p0 = -sh0 * ucls[0];
            p1 = -sh0 * ucls[UD];
        }
        float s0 = 2.f + 2.f * blk_sum(p0, red) + ubias[0];
        float s1 = 2.f + 2.f * blk_sum(p1, red) + ubias[1];
        if (j == 0) {
            float mm = fmaxf(s0, s1);
            float lse = mm + logf(expf(s0 - mm) + expf(s1 - mm));
            int am = (s1 > s0) ? 1 : 0;
            pr[3] = lse - s0;
            pr[4] = (am == 0) ? 1.f : 0.f;
        }

        float c0 = shs[2];
        float z0 = sqrtf(fmaxf(c0 * c0, 1e-8f));
        __syncthreads();
        for (int v = j; v < V_; v += 256) {
            const float* wv = wcls + (size_t)v * ZD;
            float d = -z0 * wv[0];
            for (int i = 1; i < L_; i++) d += ctxs[i] * wv[255 + i];
            sc[v] = 2.f + 2.f * d + wbias[v];
        }
        __syncthreads();
        float mx = -1e30f; int mi = 0;
        for (int v = j; v < V_; v += 256) { float x = sc[v]; if (x > mx) { mx = x; mi = v; } }
        red[j] = mx; redi[j] = mi;
        __syncthreads();
        for (int o = 128; o > 0; o >>= 1) {
            if (j < o) {
                float xo = red[j + o]; int io = redi[j + o];
                if (xo > red[j] || (xo == red[j] && io < redi[j])) { red[j] = xo; redi[j] = io; }
            }
            __syncthreads();
        }
        float gm = red[0]; int ga = redi[0];
        __syncthreads();
        float se = 0.f;
        for (int v = j; v < V_; v += 256) se += expf(sc[v] - gm);
        red[j] = se;
        __syncthreads();
        for (int o = 128; o > 0; o >>= 1) { if (j < o) red[j] += red[j + o]; __syncthreads(); }
        if (j == 0) {
            float lse = gm + logf(red[0]);
            pr[0] = lse - sc[rw];
            pr[1] = (ga == rw) ? 1.f : 0.f;
            pr[2] = 0.f;
        }
    }
}

// ---------------- finalize ----------------

__global__ __launch_bounds__(256) void finalize2(const float* __restrict__ part,
                                                 float* __restrict__ out) {
    int j = threadIdx.x;
    __shared__ float red[256][5];
    #pragma unroll
    for (int c = 0; c < 5; c++)
        red[j][c] = part[(size_t)j * 8 + c] + part[(size_t)(j + 256) * 8 + c]
                  + part[(size_t)(j + 512) * 8 + c];
    __syncthreads();
    for (int o = 128; o > 0; o >>= 1) {
        if (j < o) {
            #pragma unroll
            for (int c = 0; c < 5; c++) red[j][c] += red[j + o][c];
        }
        __syncthreads();
    }
    if (j == 0) {
        out[0] = red[0][0] / (float)B_;
        out[1] = red[0][3] / (float)B_;
        out[2] = red[0][1] / ((float)B_ + red[0][2]);
        out[3] = red[0][4] / (float)(E_ + B_);
    }
}

// ---------------- launch ----------------

extern "C" void kernel_launch(void* const* d_in, const int* in_sizes, int n_in,
                              void* d_out, int out_size, void* d_ws, size_t ws_size,
                              hipStream_t stream) {
    const int*   wid   = (const int*)d_in[0];
    const int*   nhi   = (const int*)d_in[1];
    const float* nhw   = (const float*)d_in[2];
    const int*   noi   = (const int*)d_in[3];
    const float* now_w = (const float*)d_in[4];
    const int*   bidx  = (const int*)d_in[5];
    const int*   dir   = (const int*)d_in[6];
    const int*   pt    = (const int*)d_in[7];
    const int*   rwid  = (const int*)d_in[8];
    const int*   roi   = (const int*)d_in[9];
    const float* row_w = (const float*)d_in[10];
    const float* xtv   = (const float*)d_in[11];
    const float* emb   = (const float*)d_in[12];
    const float* W0    = (const float*)d_in[13];
    const float* b0    = (const float*)d_in[14];
    const float* s0    = (const float*)d_in[15];
    const float* W1    = (const float*)d_in[16];
    const float* b1    = (const float*)d_in[17];
    const float* s1    = (const float*)d_in[18];
    const float* wcls  = (const float*)d_in[19];
    const float* wbias = (const float*)d_in[20];
    const float* ucls  = (const float*)d_in[21];
    const float* ubias = (const float*)d_in[22];

    float* ws   = (float*)d_ws;
    float* hbuf = ws;                                          // (E+1)*256 f32
    float* SC   = hbuf + (size_t)(E_ + 1) * H_;                // E*V f32
    float* part = SC + (size_t)E_ * V_;                        // 768*8 f32
    _Float16* W0P = (_Float16*)(part + 768 * 8);               // 65536 fp16
    _Float16* W1P = W0P + 65536;                               // 131072 fp16
    _Float16* Zh  = W1P + 131072;                              // E*KP fp16
    _Float16* Wh  = Zh + (size_t)E_ * KP;                      // VP*KP fp16
    float* out  = (float*)d_out;

    prep_k<<<(PREP_TOTAL + 255) / 256, 256, 0, stream>>>(W0, W1, wcls, hbuf, W0P, W1P, Wh);

    scan_flow<<<M_, 256, 0, stream>>>(hbuf, W0P, b0, s0, W1P, b1, s1,
                                      emb, wid, nhi, nhw, bidx, xtv, Zh);

    gemm_mfma<<<dim3(E_ / 64, VP / 64), 256, 0, stream>>>(Zh, Wh, wbias, SC);
    msg_ce2<<<256, 256, 0, stream>>>(SC, pt, dir, part);
    stoproot_k<<<512, 256, 0, stream>>>(hbuf, emb, xtv, wid, noi, now_w, bidx, dir,
                                        rwid, roi, row_w, wcls, wbias, ucls, ubias, part);
    finalize2<<<1, 256, 0, stream>>>(part, out);
}

// Round 16
// 832.036 us; speedup vs baseline: 1.3280x; 1.3280x over previous
//
#include <hip/hip_runtime.h>
#include <math.h>

#define T_ 64
#define M_ 256
#define K_ 6
#define B_ 256
#define H_ 256
#define L_ 128
#define V_ 780
#define E_ (T_*M_)       // 16384
#define ZD 383           // H+L-1
#define UD 638           // 2H+L-2
#define KP 384           // ZD padded for MFMA
#define VP 832           // V padded to 13*64

typedef unsigned short ushort_t;
typedef __attribute__((ext_vector_type(8))) _Float16 half8v;
typedef __attribute__((ext_vector_type(4))) _Float16 half4v;
typedef __attribute__((ext_vector_type(4))) float f32x4v;

// ---------------- helpers ----------------

__device__ __forceinline__ float blk_sum(float v, float* red) {
    int j = threadIdx.x;
    #pragma unroll
    for (int o = 32; o > 0; o >>= 1) v += __shfl_down(v, o, 64);
    __syncthreads();
    if ((j & 63) == 0) red[j >> 6] = v;
    __syncthreads();
    return red[0] + red[1] + red[2] + red[3];
}

__device__ __forceinline__ float wave_sum(float v) {
    #pragma unroll
    for (int o = 32; o > 0; o >>= 1) v += __shfl_xor(v, o, 64);
    return v;
}

__device__ __forceinline__ void wave_maxarg(float& v, int& i) {
    #pragma unroll
    for (int o = 32; o > 0; o >>= 1) {
        float vo = __shfl_xor(v, o, 64);
        int   io = __shfl_xor(i, o, 64);
        if (vo > v || (vo == v && io < i)) { v = vo; i = io; }
    }
}

__device__ __forceinline__ _Float16 f2h(float x) { return (_Float16)x; }

// LLC-coherent (agent-scope, L2-bypassing) accessors for mutable cross-step state
__device__ __forceinline__ float llc_load(const float* p) {
    return __hip_atomic_load(p, __ATOMIC_RELAXED, __HIP_MEMORY_SCOPE_AGENT);
}
__device__ __forceinline__ void llc_store(float* p, float v) {
    __hip_atomic_store(p, v, __ATOMIC_RELAXED, __HIP_MEMORY_SCOPE_AGENT);
}

// ---------------- fused prep: hbuf init (flags!) + W packs + wcls conv ----------------
// hbuf rows 0..E-1: h[0]=0 is the "not yet written" flag (written rows have
// h[0]>=1.1); these rows are NEVER read before being written (neighbor ids at
// step t are in [0,t*M) or PAD). Row E (PAD) fully = (1,0,...,0).

#define PREP_R0 ((E_ + 1) * H_)          // hbuf
#define PREP_R1 65536                    // W0P  (16*8*64*8)
#define PREP_R2 131072                   // W1P  (16*16*64*8)
#define PREP_R3 (VP * KP)                // Wh
#define PREP_TOTAL (PREP_R0 + PREP_R1 + PREP_R2 + PREP_R3)

__global__ __launch_bounds__(256) void prep_k(const float* __restrict__ W0,
                                              const float* __restrict__ W1,
                                              const float* __restrict__ wcls,
                                              float* __restrict__ hbuf,
                                              _Float16* __restrict__ W0P,
                                              _Float16* __restrict__ W1P,
                                              _Float16* __restrict__ Wh) {
    int idx = blockIdx.x * 256 + threadIdx.x;
    if (idx < PREP_R0) {
        // rows < E: all zeros (h[0]==0 is the dataflow flag). Row E: (1,0,..,0).
        hbuf[idx] = (idx >= E_ * H_ && (idx & (H_ - 1)) == 0) ? 1.f : 0.f;
        return;
    }
    idx -= PREP_R0;
    if (idx < PREP_R1) {
        // W0P[((nt*8+ks)*64+l)*8+e] = W0[(nt*16+(l&15)) * H + ks*32+(l>>4)*8+e]
        int e = idx & 7, l = (idx >> 3) & 63, ks = (idx >> 9) & 7, nt = idx >> 12;
        int jj = nt * 16 + (l & 15);
        int ii = ks * 32 + (l >> 4) * 8 + e;
        W0P[idx] = f2h(W0[(size_t)jj * H_ + ii]);
        return;
    }
    idx -= PREP_R1;
    if (idx < PREP_R2) {
        int e = idx & 7, l = (idx >> 3) & 63, ks = (idx >> 9) & 15, nt = idx >> 13;
        int jj = nt * 16 + (l & 15);
        int ii = ks * 32 + (l >> 4) * 8 + e;
        W1P[idx] = (ii < 2 * H_ - 1) ? f2h(W1[(size_t)jj * (2 * H_ - 1) + ii]) : (_Float16)0.f;
        return;
    }
    idx -= PREP_R2;
    if (idx < PREP_R3) {
        int v = idx / KP, k = idx - v * KP;
        float val = (v < V_ && k < ZD) ? wcls[(size_t)v * ZD + k] : 0.f;
        Wh[idx] = f2h(val);
    }
}

// ---------------- dataflow scan: all 64 steps, one kernel, NO global barrier ----------------
// 256 blocks (1/CU, all co-resident: 17 KB LDS / 4 waves) x 256 threads.
// Block m computes row t*M+m for t=0..63. Before each step's gather, threads
// 0..5 ACQUIRE-spin on the 6 neighbor rows' h[0] flags (written rows have
// h[0] = time >= 1.1; prep zeroed unwritten flags). Producer: wave 0 stores
// cols 1..255 relaxed-LLC, then lane 0 RELEASE-stores h[0] (its vmcnt(0)
// drains the wave's col stores first). Deps point strictly backward in t ->
// deadlock-free. Per-step MFMA body identical to rounds 11/12 (absmax 0.0).
// [Round-13 configuration — session best, 829.9 us total. Rounds 14/15
//  variants (relaxed poll, fused gather, per-wave zz) all measured equal or
//  worse; this is the reverted known-good.]

__global__ __launch_bounds__(256) void scan_flow(float* __restrict__ hbuf,
        const _Float16* __restrict__ W0P, const float* __restrict__ b0, const float* __restrict__ s0p,
        const _Float16* __restrict__ W1P, const float* __restrict__ b1, const float* __restrict__ s1p,
        const float* __restrict__ emb, const int* __restrict__ wid,
        const int* __restrict__ nhi, const float* __restrict__ nhw) {
    int tid = threadIdx.x;
    int w = tid >> 6, l = tid & 63;
    int quad = l >> 4, col = l & 15;
    int m = blockIdx.x;
    int j0 = 4 * l;

    __shared__ __align__(16) _Float16 hn16[16][264];   // rows 0..5 staged
    __shared__ __align__(16) _Float16 zz16[520];       // 511 used + pad
    __shared__ __align__(16) float Ys[6][256];
    __shared__ __align__(16) float y2s[256];

    float es0 = expf(s0p[0]);
    float es1 = expf(s1p[0]);
    float4 bj4 = *(const float4*)(b0 + j0);
    float4 b14 = *(const float4*)(b1 + j0);

    for (int t = 0; t < T_; t++) {
        int e = t * M_ + m;
        const int*   ip = nhi + e * K_;
        const float* wp = nhw + e * K_;

        // ---- dataflow wait: spin until the 6 neighbor rows are published ----
        if (tid < K_) {
            int id = ip[tid];
            if (id < E_) {
                while (__hip_atomic_load(&hbuf[(size_t)id * H_], __ATOMIC_ACQUIRE,
                                         __HIP_MEMORY_SCOPE_AGENT) < 0.5f)
                    __builtin_amdgcn_s_sleep(1);
            }
        }
        __syncthreads();                                           // deps ready for all waves

        // stage neighbor rows as fp16 (LLC-coherent loads)
        #pragma unroll
        for (int k = 0; k < K_; k++)
            hn16[k][tid] = f2h(llc_load(&hbuf[(size_t)ip[k] * H_ + tid]));
        if (tid == 0) zz16[511] = (_Float16)0.f;
        __syncthreads();                                           // B1

        // ---- W0 GEMM via MFMA: wave w -> nt 4w..4w+3, 32 MFMA/wave ----
        f32x4v acc[4];
        #pragma unroll
        for (int q = 0; q < 4; q++) acc[q] = (f32x4v){0.f, 0.f, 0.f, 0.f};
        #pragma unroll
        for (int ks = 0; ks < 8; ks++) {
            half8v afr = *(const half8v*)&hn16[col][ks * 32 + quad * 8];
            #pragma unroll
            for (int q = 0; q < 4; q++) {
                int nt = 4 * w + q;
                half8v bf = *(const half8v*)(W0P + ((size_t)(nt * 8 + ks) * 64 + l) * 8);
                acc[q] = __builtin_amdgcn_mfma_f32_16x16x32_f16(afr, bf, acc[q], 0, 0, 0);
            }
        }
        #pragma unroll
        for (int q = 0; q < 4; q++) {
            int nt = 4 * w + q;
            #pragma unroll
            for (int r = 0; r < 4; r++) {
                int row = quad * 4 + r;
                if (row < 6) Ys[row][nt * 16 + col] = acc[q][r];
            }
        }
        __syncthreads();                                           // B2

        // ---- nonlinear phase A: lane owns cols 4l..4l+3, wave-local reductions ----
        float y[K_][4];
        #pragma unroll
        for (int k = 0; k < K_; k++) {
            float4 yv = *(const float4*)&Ys[k][j0];
            y[k][0] = yv.x + bj4.x; y[k][1] = yv.y + bj4.y;
            y[k][2] = yv.z + bj4.z; y[k][3] = yv.w + bj4.w;
        }
        float ave[4] = {0.f, 0.f, 0.f, 0.f};
        float wsum = 0.f;
        #pragma unroll
        for (int k = 0; k < K_; k++) {
            float c = y[k][0] * y[k][0] + y[k][1] * y[k][1]
                    + y[k][2] * y[k][2] + y[k][3] * y[k][3];
            if (l == 0) c -= y[k][0] * y[k][0];          // exclude j==0 term
            float ssq = wave_sum(c);
            float y0k = __shfl(y[k][0], 0, 64);
            float tm  = es0 / (1.f + expf(-y0k)) + 1.1f;
            float sc  = sqrtf((tm * tm - 1.f) / fmaxf(ssq, 1e-8f));
            float wk  = wp[k];
            #pragma unroll
            for (int c2 = 0; c2 < 4; c2++) {
                float h1v = (l == 0 && c2 == 0) ? tm : y[k][c2] * sc;
                ave[c2] += wk * h1v;
            }
            wsum += wk;
        }
        float inv = 1.f / fmaxf(wsum, 1e-8f);
        float innl = 0.f;
        #pragma unroll
        for (int c2 = 0; c2 < 4; c2++) { ave[c2] *= inv; innl += ave[c2] * ave[c2]; }
        if (l == 0) innl -= 2.f * ave[0] * ave[0];       // j==0 contributes -ave0^2
        float inner = wave_sum(innl);
        float rsc = 1.f / sqrtf(fmaxf(-inner, 1e-8f));

        int wde = wid[e];
        float4 cx4 = *(const float4*)(emb + (size_t)wde * H_ + j0);
        float cx[4] = {cx4.x, cx4.y, cx4.z, cx4.w};
        if (w == 0) {
            #pragma unroll
            for (int c2 = 0; c2 < 4; c2++) {
                int j = j0 + c2;
                float h1m = ave[c2] * rsc;
                if (j == 0) {
                    zz16[0] = f2h(sqrtf(fmaxf(cx[0] * cx[0] + h1m * h1m - 1.f, 1e-8f)));
                } else {
                    zz16[j] = f2h(cx[c2]);
                    zz16[255 + j] = f2h(h1m);
                }
            }
        }
        __syncthreads();                                           // B3

        // ---- W1 GEMV via MFMA: 64 MFMA/wave, only D row 0 used ----
        f32x4v a2[4];
        #pragma unroll
        for (int q = 0; q < 4; q++) a2[q] = (f32x4v){0.f, 0.f, 0.f, 0.f};
        #pragma unroll
        for (int ks = 0; ks < 16; ks++) {
            half8v zfr = *(const half8v*)&zz16[ks * 32 + quad * 8];
            #pragma unroll
            for (int q = 0; q < 4; q++) {
                int nt = 4 * w + q;
                half8v bf = *(const half8v*)(W1P + ((size_t)(nt * 16 + ks) * 64 + l) * 8);
                a2[q] = __builtin_amdgcn_mfma_f32_16x16x32_f16(zfr, bf, a2[q], 0, 0, 0);
            }
        }
        if (quad == 0) {
            #pragma unroll
            for (int q = 0; q < 4; q++) y2s[(4 * w + q) * 16 + col] = a2[q][0];
        }
        __syncthreads();                                           // B4

        // ---- final nonlinear + publish row (wave 0 only; flag = h[0], RELEASE) ----
        if (w == 0) {
            float4 y2v = *(const float4*)&y2s[j0];
            float y2[4] = {y2v.x + b14.x, y2v.y + b14.y, y2v.z + b14.z, y2v.w + b14.w};
            float c2s = y2[0] * y2[0] + y2[1] * y2[1] + y2[2] * y2[2] + y2[3] * y2[3];
            if (l == 0) c2s -= y2[0] * y2[0];
            float ssq2 = wave_sum(c2s);
            float y20 = __shfl(y2[0], 0, 64);
            float tm2 = es1 / (1.f + expf(-y20)) + 1.1f;
            float sc2 = sqrtf((tm2 * tm2 - 1.f) / fmaxf(ssq2, 1e-8f));
            float* hr = hbuf + (size_t)e * H_ + j0;
            // cols != flag first (relaxed)
            llc_store(hr + 1, y2[1] * sc2);
            llc_store(hr + 2, y2[2] * sc2);
            llc_store(hr + 3, y2[3] * sc2);
            if (l != 0) llc_store(hr + 0, y2[0] * sc2);
            // publish: lane 0's RELEASE store of h[0] drains the wave's stores
            if (l == 0)
                __hip_atomic_store(&hbuf[(size_t)e * H_], tm2,
                                   __ATOMIC_RELEASE, __HIP_MEMORY_SCOPE_AGENT);
        }
        // no global barrier: consumers gate on the flag
        if (t < T_ - 1) __syncthreads();
    }
}

// ---------------- build Zh (fp16, K padded) with sign-folded z0 ----------------

__global__ __launch_bounds__(256) void zbuild2(const float* __restrict__ hbuf,
                                               const float* __restrict__ xtv,
                                               const int* __restrict__ bidx,
                                               _Float16* __restrict__ Zh) {
    int e = blockIdx.x, j = threadIdx.x;
    int bi = bidx[e];
    _Float16* zr = Zh + (size_t)e * KP;
    if (j == 0) {
        float nh0 = hbuf[(size_t)e * H_];
        float c0  = xtv[(size_t)bi * L_];
        float z0  = sqrtf(fmaxf(nh0 * nh0 + c0 * c0 - 1.f, 1e-8f));
        zr[0] = f2h(-z0);   // fold the centroid's -x0*cls0 sign here
    } else {
        zr[j] = f2h(hbuf[(size_t)e * H_ + j]);
    }
    if (j < 128) {
        int c = 256 + j;                       // 256..383
        float v = (c <= 382) ? xtv[(size_t)bi * L_ + (c - 255)] : 0.f;
        zr[c] = f2h(v);
    }
}

// ---------------- msg scores GEMM (MFMA fp16): SC = 2 + 2*(Z @ wcls^T) + wbias ----------------

__global__ __launch_bounds__(256) void gemm_mfma(const _Float16* __restrict__ Zh,
                                                 const _Float16* __restrict__ Wh,
                                                 const float* __restrict__ wbias,
                                                 float* __restrict__ SC) {
    __shared__ __align__(16) _Float16 As[64][40];
    __shared__ __align__(16) _Float16 Bs[64][40];
    int tid = threadIdx.x;
    int w = tid >> 6, l = tid & 63;
    int m0 = blockIdx.x * 64;
    int n0 = blockIdx.y * 64;
    int r16 = l & 15, q8 = (l >> 4) * 8;

    int srow = tid >> 2;            // 0..63
    int schunk = (tid & 3) * 8;     // 0,8,16,24

    f32x4v acc[4];
    #pragma unroll
    for (int mt = 0; mt < 4; mt++) acc[mt] = (f32x4v){0.f, 0.f, 0.f, 0.f};

    for (int ks = 0; ks < KP / 32; ks++) {
        int k0 = ks * 32;
        __syncthreads();
        *(uint4*)&As[srow][schunk] = *(const uint4*)(Zh + (size_t)(m0 + srow) * KP + k0 + schunk);
        *(uint4*)&Bs[srow][schunk] = *(const uint4*)(Wh + (size_t)(n0 + srow) * KP + k0 + schunk);
        __syncthreads();

        half8v bfr = *(const half8v*)(&Bs[w * 16 + r16][q8]);
        #pragma unroll
        for (int mt = 0; mt < 4; mt++) {
            half8v afr = *(const half8v*)(&As[mt * 16 + r16][q8]);
            acc[mt] = __builtin_amdgcn_mfma_f32_16x16x32_f16(afr, bfr, acc[mt], 0, 0, 0);
        }
    }

    int n = n0 + w * 16 + r16;
    if (n < V_) {
        float bias = wbias[n];
        #pragma unroll
        for (int mt = 0; mt < 4; mt++) {
            #pragma unroll
            for (int r = 0; r < 4; r++) {
                int mrow = m0 + mt * 16 + (l >> 4) * 4 + r;
                SC[(size_t)mrow * V_ + n] = 2.f + 2.f * acc[mt][r] + bias;
            }
        }
    }
}

// ---------------- msg CE (masked by direction), wave-per-row, no atomics ----------------

__global__ __launch_bounds__(256) void msg_ce2(const float* __restrict__ SC,
                                               const int* __restrict__ pt,
                                               const int* __restrict__ dir,
                                               float* __restrict__ part) {
    int w = threadIdx.x >> 6, l = threadIdx.x & 63;
    int wg = blockIdx.x * 4 + w;     // 0..1023
    float lloss = 0.f, lhit = 0.f, lpm = 0.f;
    for (int i = 0; i < 16; i++) {
        int e = wg * 16 + i;
        const float* s = SC + (size_t)e * V_;
        float sv[13];
        float mx = -1e30f; int mi = 0;
        #pragma unroll
        for (int ii = 0; ii < 13; ii++) {
            int v = l + ii * 64;
            float x = (v < V_) ? s[v] : -1e30f;
            sv[ii] = x;
            if (x > mx) { mx = x; mi = v; }
        }
        wave_maxarg(mx, mi);
        float se = 0.f;
        #pragma unroll
        for (int ii = 0; ii < 13; ii++) se += expf(sv[ii] - mx);
        se = wave_sum(se);
        if (l == 0) {
            int tgt = pt[e];
            float lse = mx + logf(se);
            float pm = (float)dir[e];
            lloss += pm * (lse - s[tgt]);
            lhit  += pm * ((mi == tgt) ? 1.f : 0.f);
            lpm   += pm;
        }
    }
    __shared__ float red[4][3];
    if (l == 0) { red[w][0] = lloss; red[w][1] = lhit; red[w][2] = lpm; }
    __syncthreads();
    if (threadIdx.x == 0) {
        float* pr = part + (size_t)blockIdx.x * 8;
        pr[0] = red[0][0] + red[1][0] + red[2][0] + red[3][0];
        pr[1] = red[0][1] + red[1][1] + red[2][1] + red[3][1];
        pr[2] = red[0][2] + red[1][2] + red[2][2] + red[3][2];
        pr[3] = 0.f; pr[4] = 0.f;
    }
}

// ---------------- fused stop head (blocks 0..255) + root (blocks 256..511) ----------------

__global__ __launch_bounds__(256) void stoproot_k(const float* __restrict__ hbuf,
        const float* __restrict__ emb, const float* __restrict__ xtv,
        const int* __restrict__ wid, const int* __restrict__ noi, const float* __restrict__ now_w,
        const int* __restrict__ bidx, const int* __restrict__ dir,
        const int* __restrict__ rwid, const int* __restrict__ roi, const float* __restrict__ row_w,
        const float* __restrict__ wcls, const float* __restrict__ wbias,
        const float* __restrict__ ucls, const float* __restrict__ ubias,
        float* __restrict__ part) {
    __shared__ float red[256];
    __shared__ int   redi[256];
    __shared__ float shs[4];
    __shared__ float ctxs[L_];
    __shared__ float sc[V_];
    __shared__ float red2[4][2];

    if (blockIdx.x < 256) {
        // ---------- stop head per message (64 e's per block, wave-per-row) ----------
        int w = threadIdx.x >> 6, l = threadIdx.x & 63;
        int wg = blockIdx.x * 4 + w;

        float ua0[4], ub0[4], ua1[4], ub1[4], uc0[2], uc1[2];
        #pragma unroll
        for (int s = 0; s < 4; s++) {
            int j = s * 64 + l;
            ua0[s] = ucls[j];        ub0[s] = ucls[255 + j];
            ua1[s] = ucls[UD + j];   ub1[s] = ucls[UD + 255 + j];
        }
        #pragma unroll
        for (int s = 0; s < 2; s++) {
            int j = s * 64 + l;
            uc0[s] = ucls[510 + j];  uc1[s] = ucls[UD + 510 + j];
        }
        float u00 = ucls[0], u10 = ucls[UD];
        float ubs0 = ubias[0], ubs1 = ubias[1];

        float lloss = 0.f, lhit = 0.f;
        for (int i = 0; i < 16; i++) {
            int e = wg * 16 + i;
            const int*   ip = noi + e * K_;
            const float* wp = now_w + e * K_;
            float ave[4] = {0.f, 0.f, 0.f, 0.f};
            float wsum = 0.f;
            #pragma unroll
            for (int k = 0; k < K_; k++) {
                int id = ip[k]; float wt = wp[k];
                wsum += wt;
                const float* hr = hbuf + (size_t)id * H_;
                #pragma unroll
                for (int s = 0; s < 4; s++) ave[s] += wt * hr[s * 64 + l];
            }
            float inv = 1.f / fmaxf(wsum, 1e-8f);
            float innl = 0.f;
            #pragma unroll
            for (int s = 0; s < 4; s++) { ave[s] *= inv; innl += ave[s] * ave[s]; }
            if (l == 0) innl -= 2.f * ave[0] * ave[0];
            float inner = wave_sum(innl);
            float cs = 1.f / sqrtf(fmaxf(-inner, 1e-8f));

            int we = wid[e], bi = bidx[e];
            const float* er = emb + (size_t)we * H_;
            const float* cr = xtv + (size_t)bi * L_;

            float p0 = 0.f, p1 = 0.f;
            #pragma unroll
            for (int s = 0; s < 4; s++) {
                float cx = er[s * 64 + l];
                float co = ave[s] * cs;
                if (s == 0 && l == 0) {
                    float ctx0 = cr[0];
                    float t1sq = fmaxf(cx * cx + co * co - 1.f, 1e-8f);
                    float sh0 = sqrtf(fmaxf(t1sq + ctx0 * ctx0 - 1.f, 1e-8f));
                    p0 += -sh0 * u00; p1 += -sh0 * u10;
                } else {
                    p0 += cx * ua0[s] + co * ub0[s];
                    p1 += cx * ua1[s] + co * ub1[s];
                }
                if (s < 2) {
                    int j = s * 64 + l;
                    if (j >= 1) {
                        float ctx = cr[j];
                        p0 += ctx * uc0[s]; p1 += ctx * uc1[s];
                    }
                }
            }
            p0 = wave_sum(p0); p1 = wave_sum(p1);
            if (l == 0) {
                float sc0 = 2.f + 2.f * p0 + ubs0;
                float sc1 = 2.f + 2.f * p1 + ubs1;
                int tgt = dir[e];
                float mm = fmaxf(sc0, sc1);
                float lse = mm + logf(expf(sc0 - mm) + expf(sc1 - mm));
                lloss += lse - ((tgt == 0) ? sc0 : sc1);
                int am = (sc1 > sc0) ? 1 : 0;
                lhit += (am == tgt) ? 1.f : 0.f;
            }
        }
        if (l == 0) { red2[w][0] = lloss; red2[w][1] = lhit; }
        __syncthreads();
        if (threadIdx.x == 0) {
            float* pr = part + (size_t)(256 + blockIdx.x) * 8;
            pr[0] = 0.f; pr[1] = 0.f; pr[2] = 0.f;
            pr[3] = red2[0][0] + red2[1][0] + red2[2][0] + red2[3][0];
            pr[4] = red2[0][1] + red2[1][1] + red2[2][1] + red2[3][1];
        }
    } else {
        // ---------- root: stop head + pred head ----------
        int b = blockIdx.x - 256, j = threadIdx.x;
        float* pr = part + (size_t)(512 + b) * 8;

        const int*   ip = roi + b * K_;
        const float* wp = row_w + b * K_;
        float ave = 0.f, wsum = 0.f;
        #pragma unroll
        for (int k = 0; k < K_; k++) {
            int id = ip[k]; float w = wp[k];
            ave += w * hbuf[(size_t)id * H_ + j];
            wsum += w;
        }
        ave /= fmaxf(wsum, 1e-8f);
        float inner = blk_sum((j == 0) ? -ave * ave : ave * ave, red);
        float ro = ave / sqrtf(fmaxf(-inner, 1e-8f));

        int   rw = rwid[b];
        float er = emb[(size_t)rw * H_ + j];
        float ctxj = (j < L_) ? xtv[(size_t)b * L_ + j] : 0.f;
        if (j == 0) { shs[0] = er; shs[1] = ro; shs[2] = ctxj; }
        if (j < L_) ctxs[j] = ctxj;
        __syncthreads();
        float t1sq = fmaxf(shs[0] * shs[0] + shs[1] * shs[1] - 1.f, 1e-8f);
        float sh0  = sqrtf(fmaxf(t1sq + shs[2] * shs[2] - 1.f, 1e-8f));

        float p0, p1;
        if (j >= 1) {
            p0 = er * ucls[j] + ro * ucls[255 + j];
            p1 = er * ucls[UD + j] + ro * ucls[UD + 255 + j];
            if (j < L_) { p0 += ctxj * ucls[510 + j]; p1 += ctxj * ucls[UD + 510 + j]; }
        } else {
            p0 = -sh0 * ucls[0];
            p1 = -sh0 * ucls[UD];
        }
        float s0 = 2.f + 2.f * blk_sum(p0, red) + ubias[0];
        float s1 = 2.f + 2.f * blk_sum(p1, red) + ubias[1];
        if (j == 0) {
            float mm = fmaxf(s0, s1);
            float lse = mm + logf(expf(s0 - mm) + expf(s1 - mm));
            int am = (s1 > s0) ? 1 : 0;
            pr[3] = lse - s0;
            pr[4] = (am == 0) ? 1.f : 0.f;
        }

        float c0 = shs[2];
        float z0 = sqrtf(fmaxf(c0 * c0, 1e-8f));
        __syncthreads();
        for (int v = j; v < V_; v += 256) {
            const float* wv = wcls + (size_t)v * ZD;
            float d = -z0 * wv[0];
            for (int i = 1; i < L_; i++) d += ctxs[i] * wv[255 + i];
            sc[v] = 2.f + 2.f * d + wbias[v];
        }
        __syncthreads();
        float mx = -1e30f; int mi = 0;
        for (int v = j; v < V_; v += 256) { float x = sc[v]; if (x > mx) { mx = x; mi = v; } }
        red[j] = mx; redi[j] = mi;
        __syncthreads();
        for (int o = 128; o > 0; o >>= 1) {
            if (j < o) {
                float xo = red[j + o]; int io = redi[j + o];
                if (xo > red[j] || (xo == red[j] && io < redi[j])) { red[j] = xo; redi[j] = io; }
            }
            __syncthreads();
        }
        float gm = red[0]; int ga = redi[0];
        __syncthreads();
        float se = 0.f;
        for (int v = j; v < V_; v += 256) se += expf(sc[v] - gm);
        red[j] = se;
        __syncthreads();
        for (int o = 128; o > 0; o >>= 1) { if (j < o) red[j] += red[j + o]; __syncthreads(); }
        if (j == 0) {
            float lse = gm + logf(red[0]);
            pr[0] = lse - sc[rw];
            pr[1] = (ga == rw) ? 1.f : 0.f;
            pr[2] = 0.f;
        }
    }
}

// ---------------- finalize ----------------

__global__ __launch_bounds__(256) void finalize2(const float* __restrict__ part,
                                                 float* __restrict__ out) {
    int j = threadIdx.x;
    __shared__ float red[256][5];
    #pragma unroll
    for (int c = 0; c < 5; c++)
        red[j][c] = part[(size_t)j * 8 + c] + part[(size_t)(j + 256) * 8 + c]
                  + part[(size_t)(j + 512) * 8 + c];
    __syncthreads();
    for (int o = 128; o > 0; o >>= 1) {
        if (j < o) {
            #pragma unroll
            for (int c = 0; c < 5; c++) red[j][c] += red[j + o][c];
        }
        __syncthreads();
    }
    if (j == 0) {
        out[0] = red[0][0] / (float)B_;
        out[1] = red[0][3] / (float)B_;
        out[2] = red[0][1] / ((float)B_ + red[0][2]);
        out[3] = red[0][4] / (float)(E_ + B_);
    }
}

// ---------------- launch ----------------

extern "C" void kernel_launch(void* const* d_in, const int* in_sizes, int n_in,
                              void* d_out, int out_size, void* d_ws, size_t ws_size,
                              hipStream_t stream) {
    const int*   wid   = (const int*)d_in[0];
    const int*   nhi   = (const int*)d_in[1];
    const float* nhw   = (const float*)d_in[2];
    const int*   noi   = (const int*)d_in[3];
    const float* now_w = (const float*)d_in[4];
    const int*   bidx  = (const int*)d_in[5];
    const int*   dir   = (const int*)d_in[6];
    const int*   pt    = (const int*)d_in[7];
    const int*   rwid  = (const int*)d_in[8];
    const int*   roi   = (const int*)d_in[9];
    const float* row_w = (const float*)d_in[10];
    const float* xtv   = (const float*)d_in[11];
    const float* emb   = (const float*)d_in[12];
    const float* W0    = (const float*)d_in[13];
    const float* b0    = (const float*)d_in[14];
    const float* s0    = (const float*)d_in[15];
    const float* W1    = (const float*)d_in[16];
    const float* b1    = (const float*)d_in[17];
    const float* s1    = (const float*)d_in[18];
    const float* wcls  = (const float*)d_in[19];
    const float* wbias = (const float*)d_in[20];
    const float* ucls  = (const float*)d_in[21];
    const float* ubias = (const float*)d_in[22];

    float* ws   = (float*)d_ws;
    float* hbuf = ws;                                          // (E+1)*256 f32
    float* SC   = hbuf + (size_t)(E_ + 1) * H_;                // E*V f32
    float* part = SC + (size_t)E_ * V_;                        // 768*8 f32
    _Float16* W0P = (_Float16*)(part + 768 * 8);               // 65536 fp16
    _Float16* W1P = W0P + 65536;                               // 131072 fp16
    _Float16* Zh  = W1P + 131072;                              // E*KP fp16
    _Float16* Wh  = Zh + (size_t)E_ * KP;                      // VP*KP fp16
    float* out  = (float*)d_out;

    prep_k<<<(PREP_TOTAL + 255) / 256, 256, 0, stream>>>(W0, W1, wcls, hbuf, W0P, W1P, Wh);

    scan_flow<<<M_, 256, 0, stream>>>(hbuf, W0P, b0, s0, W1P, b1, s1,
                                      emb, wid, nhi, nhw);

    zbuild2<<<E_, 256, 0, stream>>>(hbuf, xtv, bidx, Zh);
    gemm_mfma<<<dim3(E_ / 64, VP / 64), 256, 0, stream>>>(Zh, Wh, wbias, SC);
    msg_ce2<<<256, 256, 0, stream>>>(SC, pt, dir, part);
    stoproot_k<<<512, 256, 0, stream>>>(hbuf, emb, xtv, wid, noi, now_w, bidx, dir,
                                        rwid, roi, row_w, wcls, wbias, ucls, ubias, part);
    finalize2<<<1, 256, 0, stream>>>(part, out);
}

// Round 17
// 825.803 us; speedup vs baseline: 1.3380x; 1.0075x over previous
//
#include <hip/hip_runtime.h>
#include <math.h>

#define T_ 64
#define M_ 256
#define K_ 6
#define B_ 256
#define H_ 256
#define L_ 128
#define V_ 780
#define E_ (T_*M_)       // 16384
#define ZD 383           // H+L-1
#define UD 638           // 2H+L-2
#define KP 384           // ZD padded for MFMA
#define VP 832           // V padded to 13*64

typedef unsigned short ushort_t;
typedef __attribute__((ext_vector_type(8))) _Float16 half8v;
typedef __attribute__((ext_vector_type(4))) _Float16 half4v;
typedef __attribute__((ext_vector_type(4))) float f32x4v;

// ---------------- helpers ----------------

__device__ __forceinline__ float blk_sum(float v, float* red) {
    int j = threadIdx.x;
    #pragma unroll
    for (int o = 32; o > 0; o >>= 1) v += __shfl_down(v, o, 64);
    __syncthreads();
    if ((j & 63) == 0) red[j >> 6] = v;
    __syncthreads();
    return red[0] + red[1] + red[2] + red[3];
}

__device__ __forceinline__ float wave_sum(float v) {
    #pragma unroll
    for (int o = 32; o > 0; o >>= 1) v += __shfl_xor(v, o, 64);
    return v;
}

__device__ __forceinline__ void wave_maxarg(float& v, int& i) {
    #pragma unroll
    for (int o = 32; o > 0; o >>= 1) {
        float vo = __shfl_xor(v, o, 64);
        int   io = __shfl_xor(i, o, 64);
        if (vo > v || (vo == v && io < i)) { v = vo; i = io; }
    }
}

__device__ __forceinline__ _Float16 f2h(float x) { return (_Float16)x; }

// LLC-coherent (agent-scope, L2-bypassing) accessors for mutable cross-step state
__device__ __forceinline__ float llc_load(const float* p) {
    return __hip_atomic_load(p, __ATOMIC_RELAXED, __HIP_MEMORY_SCOPE_AGENT);
}
__device__ __forceinline__ void llc_store(float* p, float v) {
    __hip_atomic_store(p, v, __ATOMIC_RELAXED, __HIP_MEMORY_SCOPE_AGENT);
}

// ---------------- fused prep: hbuf init (flags!) + W packs + wcls conv ----------------
// hbuf rows 0..E-1: h[0]=0 is the "not yet written" flag (written rows have
// h[0]>=1.1); these rows are NEVER read before being written (neighbor ids at
// step t are in [0,t*M) or PAD). Row E (PAD) fully = (1,0,...,0).

#define PREP_R0 ((E_ + 1) * H_)          // hbuf
#define PREP_R1 65536                    // W0P  (16*8*64*8)
#define PREP_R2 131072                   // W1P  (16*16*64*8)
#define PREP_R3 (VP * KP)                // Wh
#define PREP_TOTAL (PREP_R0 + PREP_R1 + PREP_R2 + PREP_R3)

__global__ __launch_bounds__(256) void prep_k(const float* __restrict__ W0,
                                              const float* __restrict__ W1,
                                              const float* __restrict__ wcls,
                                              float* __restrict__ hbuf,
                                              _Float16* __restrict__ W0P,
                                              _Float16* __restrict__ W1P,
                                              _Float16* __restrict__ Wh) {
    int idx = blockIdx.x * 256 + threadIdx.x;
    if (idx < PREP_R0) {
        // rows < E: all zeros (h[0]==0 is the dataflow flag). Row E: (1,0,..,0).
        hbuf[idx] = (idx >= E_ * H_ && (idx & (H_ - 1)) == 0) ? 1.f : 0.f;
        return;
    }
    idx -= PREP_R0;
    if (idx < PREP_R1) {
        // W0P[((nt*8+ks)*64+l)*8+e] = W0[(nt*16+(l&15)) * H + ks*32+(l>>4)*8+e]
        int e = idx & 7, l = (idx >> 3) & 63, ks = (idx >> 9) & 7, nt = idx >> 12;
        int jj = nt * 16 + (l & 15);
        int ii = ks * 32 + (l >> 4) * 8 + e;
        W0P[idx] = f2h(W0[(size_t)jj * H_ + ii]);
        return;
    }
    idx -= PREP_R1;
    if (idx < PREP_R2) {
        int e = idx & 7, l = (idx >> 3) & 63, ks = (idx >> 9) & 15, nt = idx >> 13;
        int jj = nt * 16 + (l & 15);
        int ii = ks * 32 + (l >> 4) * 8 + e;
        W1P[idx] = (ii < 2 * H_ - 1) ? f2h(W1[(size_t)jj * (2 * H_ - 1) + ii]) : (_Float16)0.f;
        return;
    }
    idx -= PREP_R2;
    if (idx < PREP_R3) {
        int v = idx / KP, k = idx - v * KP;
        float val = (v < V_ && k < ZD) ? wcls[(size_t)v * ZD + k] : 0.f;
        Wh[idx] = f2h(val);
    }
}

// ---------------- dataflow scan: all 64 steps, one kernel, NO global barrier ----------------
// [Round-13 configuration — session best; six sync mechanisms measured, this
//  (acquire-spin dataflow) is the floor at ~10 us per dependency level.]

__global__ __launch_bounds__(256) void scan_flow(float* __restrict__ hbuf,
        const _Float16* __restrict__ W0P, const float* __restrict__ b0, const float* __restrict__ s0p,
        const _Float16* __restrict__ W1P, const float* __restrict__ b1, const float* __restrict__ s1p,
        const float* __restrict__ emb, const int* __restrict__ wid,
        const int* __restrict__ nhi, const float* __restrict__ nhw) {
    int tid = threadIdx.x;
    int w = tid >> 6, l = tid & 63;
    int quad = l >> 4, col = l & 15;
    int m = blockIdx.x;
    int j0 = 4 * l;

    __shared__ __align__(16) _Float16 hn16[16][264];   // rows 0..5 staged
    __shared__ __align__(16) _Float16 zz16[520];       // 511 used + pad
    __shared__ __align__(16) float Ys[6][256];
    __shared__ __align__(16) float y2s[256];

    float es0 = expf(s0p[0]);
    float es1 = expf(s1p[0]);
    float4 bj4 = *(const float4*)(b0 + j0);
    float4 b14 = *(const float4*)(b1 + j0);

    for (int t = 0; t < T_; t++) {
        int e = t * M_ + m;
        const int*   ip = nhi + e * K_;
        const float* wp = nhw + e * K_;

        // ---- dataflow wait: spin until the 6 neighbor rows are published ----
        if (tid < K_) {
            int id = ip[tid];
            if (id < E_) {
                while (__hip_atomic_load(&hbuf[(size_t)id * H_], __ATOMIC_ACQUIRE,
                                         __HIP_MEMORY_SCOPE_AGENT) < 0.5f)
                    __builtin_amdgcn_s_sleep(1);
            }
        }
        __syncthreads();                                           // deps ready for all waves

        // stage neighbor rows as fp16 (LLC-coherent loads)
        #pragma unroll
        for (int k = 0; k < K_; k++)
            hn16[k][tid] = f2h(llc_load(&hbuf[(size_t)ip[k] * H_ + tid]));
        if (tid == 0) zz16[511] = (_Float16)0.f;
        __syncthreads();                                           // B1

        // ---- W0 GEMM via MFMA: wave w -> nt 4w..4w+3, 32 MFMA/wave ----
        f32x4v acc[4];
        #pragma unroll
        for (int q = 0; q < 4; q++) acc[q] = (f32x4v){0.f, 0.f, 0.f, 0.f};
        #pragma unroll
        for (int ks = 0; ks < 8; ks++) {
            half8v afr = *(const half8v*)&hn16[col][ks * 32 + quad * 8];
            #pragma unroll
            for (int q = 0; q < 4; q++) {
                int nt = 4 * w + q;
                half8v bf = *(const half8v*)(W0P + ((size_t)(nt * 8 + ks) * 64 + l) * 8);
                acc[q] = __builtin_amdgcn_mfma_f32_16x16x32_f16(afr, bf, acc[q], 0, 0, 0);
            }
        }
        #pragma unroll
        for (int q = 0; q < 4; q++) {
            int nt = 4 * w + q;
            #pragma unroll
            for (int r = 0; r < 4; r++) {
                int row = quad * 4 + r;
                if (row < 6) Ys[row][nt * 16 + col] = acc[q][r];
            }
        }
        __syncthreads();                                           // B2

        // ---- nonlinear phase A: lane owns cols 4l..4l+3, wave-local reductions ----
        float y[K_][4];
        #pragma unroll
        for (int k = 0; k < K_; k++) {
            float4 yv = *(const float4*)&Ys[k][j0];
            y[k][0] = yv.x + bj4.x; y[k][1] = yv.y + bj4.y;
            y[k][2] = yv.z + bj4.z; y[k][3] = yv.w + bj4.w;
        }
        float ave[4] = {0.f, 0.f, 0.f, 0.f};
        float wsum = 0.f;
        #pragma unroll
        for (int k = 0; k < K_; k++) {
            float c = y[k][0] * y[k][0] + y[k][1] * y[k][1]
                    + y[k][2] * y[k][2] + y[k][3] * y[k][3];
            if (l == 0) c -= y[k][0] * y[k][0];          // exclude j==0 term
            float ssq = wave_sum(c);
            float y0k = __shfl(y[k][0], 0, 64);
            float tm  = es0 / (1.f + expf(-y0k)) + 1.1f;
            float sc  = sqrtf((tm * tm - 1.f) / fmaxf(ssq, 1e-8f));
            float wk  = wp[k];
            #pragma unroll
            for (int c2 = 0; c2 < 4; c2++) {
                float h1v = (l == 0 && c2 == 0) ? tm : y[k][c2] * sc;
                ave[c2] += wk * h1v;
            }
            wsum += wk;
        }
        float inv = 1.f / fmaxf(wsum, 1e-8f);
        float innl = 0.f;
        #pragma unroll
        for (int c2 = 0; c2 < 4; c2++) { ave[c2] *= inv; innl += ave[c2] * ave[c2]; }
        if (l == 0) innl -= 2.f * ave[0] * ave[0];       // j==0 contributes -ave0^2
        float inner = wave_sum(innl);
        float rsc = 1.f / sqrtf(fmaxf(-inner, 1e-8f));

        int wde = wid[e];
        float4 cx4 = *(const float4*)(emb + (size_t)wde * H_ + j0);
        float cx[4] = {cx4.x, cx4.y, cx4.z, cx4.w};
        if (w == 0) {
            #pragma unroll
            for (int c2 = 0; c2 < 4; c2++) {
                int j = j0 + c2;
                float h1m = ave[c2] * rsc;
                if (j == 0) {
                    zz16[0] = f2h(sqrtf(fmaxf(cx[0] * cx[0] + h1m * h1m - 1.f, 1e-8f)));
                } else {
                    zz16[j] = f2h(cx[c2]);
                    zz16[255 + j] = f2h(h1m);
                }
            }
        }
        __syncthreads();                                           // B3

        // ---- W1 GEMV via MFMA: 64 MFMA/wave, only D row 0 used ----
        f32x4v a2[4];
        #pragma unroll
        for (int q = 0; q < 4; q++) a2[q] = (f32x4v){0.f, 0.f, 0.f, 0.f};
        #pragma unroll
        for (int ks = 0; ks < 16; ks++) {
            half8v zfr = *(const half8v*)&zz16[ks * 32 + quad * 8];
            #pragma unroll
            for (int q = 0; q < 4; q++) {
                int nt = 4 * w + q;
                half8v bf = *(const half8v*)(W1P + ((size_t)(nt * 16 + ks) * 64 + l) * 8);
                a2[q] = __builtin_amdgcn_mfma_f32_16x16x32_f16(zfr, bf, a2[q], 0, 0, 0);
            }
        }
        if (quad == 0) {
            #pragma unroll
            for (int q = 0; q < 4; q++) y2s[(4 * w + q) * 16 + col] = a2[q][0];
        }
        __syncthreads();                                           // B4

        // ---- final nonlinear + publish row (wave 0 only; flag = h[0], RELEASE) ----
        if (w == 0) {
            float4 y2v = *(const float4*)&y2s[j0];
            float y2[4] = {y2v.x + b14.x, y2v.y + b14.y, y2v.z + b14.z, y2v.w + b14.w};
            float c2s = y2[0] * y2[0] + y2[1] * y2[1] + y2[2] * y2[2] + y2[3] * y2[3];
            if (l == 0) c2s -= y2[0] * y2[0];
            float ssq2 = wave_sum(c2s);
            float y20 = __shfl(y2[0], 0, 64);
            float tm2 = es1 / (1.f + expf(-y20)) + 1.1f;
            float sc2 = sqrtf((tm2 * tm2 - 1.f) / fmaxf(ssq2, 1e-8f));
            float* hr = hbuf + (size_t)e * H_ + j0;
            // cols != flag first (relaxed)
            llc_store(hr + 1, y2[1] * sc2);
            llc_store(hr + 2, y2[2] * sc2);
            llc_store(hr + 3, y2[3] * sc2);
            if (l != 0) llc_store(hr + 0, y2[0] * sc2);
            // publish: lane 0's RELEASE store of h[0] drains the wave's stores
            if (l == 0)
                __hip_atomic_store(&hbuf[(size_t)e * H_], tm2,
                                   __ATOMIC_RELEASE, __HIP_MEMORY_SCOPE_AGENT);
        }
        // no global barrier: consumers gate on the flag
        if (t < T_ - 1) __syncthreads();
    }
}

// ---------------- build Zh (fp16, K padded) with sign-folded z0 ----------------

__global__ __launch_bounds__(256) void zbuild2(const float* __restrict__ hbuf,
                                               const float* __restrict__ xtv,
                                               const int* __restrict__ bidx,
                                               _Float16* __restrict__ Zh) {
    int e = blockIdx.x, j = threadIdx.x;
    int bi = bidx[e];
    _Float16* zr = Zh + (size_t)e * KP;
    if (j == 0) {
        float nh0 = hbuf[(size_t)e * H_];
        float c0  = xtv[(size_t)bi * L_];
        float z0  = sqrtf(fmaxf(nh0 * nh0 + c0 * c0 - 1.f, 1e-8f));
        zr[0] = f2h(-z0);   // fold the centroid's -x0*cls0 sign here
    } else {
        zr[j] = f2h(hbuf[(size_t)e * H_ + j]);
    }
    if (j < 128) {
        int c = 256 + j;                       // 256..383
        float v = (c <= 382) ? xtv[(size_t)bi * L_ + (c - 255)] : 0.f;
        zr[c] = f2h(v);
    }
}

// ---------------- fused msg GEMM + CE (flash-style): no SC materialization ----------------
// 256 blocks x 256 threads, 1 block/CU (116 KB LDS). Block owns 64 e-rows.
// A-tile (64x384 fp16) staged once; loop 13 N-tiles: stage B-tile, 12 K-step
// MFMA, scores -> LDS tile, online per-row max/argmax/logsumexp update +
// target-score capture. Tie-break = np.argmax first-index (ascending tiles,
// strict >, equal -> smaller index). Same MFMA fragment layout as before.

__global__ __launch_bounds__(256) void gemm_ce(const _Float16* __restrict__ Zh,
                                               const _Float16* __restrict__ Wh,
                                               const float* __restrict__ wbias,
                                               const int* __restrict__ pt,
                                               const int* __restrict__ dir,
                                               float* __restrict__ part) {
    __shared__ __align__(16) _Float16 As[64][392];
    __shared__ __align__(16) _Float16 Bsf[64][392];
    __shared__ __align__(16) float SCs[64][68];
    __shared__ float rmax[64], rsum[64], rval[64];
    __shared__ int   rargi[64];

    int tid = threadIdx.x;
    int w = tid >> 6, l = tid & 63;
    int r16 = l & 15, quad = l >> 4;
    int q8 = quad * 8;
    int m0 = blockIdx.x * 64;

    // stage A-tile once (64 rows x 384 fp16; 12 x half8 per thread)
    #pragma unroll
    for (int i = 0; i < 12; i++) {
        int u = tid + i * 256;
        int row = u / 48, c8 = (u % 48) * 8;
        *(uint4*)&As[row][c8] = *(const uint4*)(Zh + (size_t)(m0 + row) * KP + c8);
    }
    if (tid < 64) {
        rmax[tid] = -1e30f; rsum[tid] = 0.f; rargi[tid] = 0; rval[tid] = 0.f;
    }
    __syncthreads();

    for (int nt = 0; nt < 13; nt++) {
        int n0 = nt * 64;
        // stage B N-tile
        #pragma unroll
        for (int i = 0; i < 12; i++) {
            int u = tid + i * 256;
            int row = u / 48, c8 = (u % 48) * 8;
            *(uint4*)&Bsf[row][c8] = *(const uint4*)(Wh + (size_t)(n0 + row) * KP + c8);
        }
        __syncthreads();    // B ready; also guards SCs reuse

        f32x4v acc[4];
        #pragma unroll
        for (int mt = 0; mt < 4; mt++) acc[mt] = (f32x4v){0.f, 0.f, 0.f, 0.f};
        #pragma unroll
        for (int ks = 0; ks < 12; ks++) {
            half8v bfr = *(const half8v*)&Bsf[w * 16 + r16][ks * 32 + q8];
            #pragma unroll
            for (int mt = 0; mt < 4; mt++) {
                half8v afr = *(const half8v*)&As[mt * 16 + r16][ks * 32 + q8];
                acc[mt] = __builtin_amdgcn_mfma_f32_16x16x32_f16(afr, bfr, acc[mt], 0, 0, 0);
            }
        }
        int ncol = n0 + w * 16 + r16;
        float bias = (ncol < V_) ? wbias[ncol] : 0.f;
        #pragma unroll
        for (int mt = 0; mt < 4; mt++) {
            #pragma unroll
            for (int r = 0; r < 4; r++)
                SCs[mt * 16 + quad * 4 + r][w * 16 + r16] = 2.f + 2.f * acc[mt][r] + bias;
        }
        __syncthreads();    // scores tile ready

        // online CE update: thread -> row tid>>2, cols (tid&3)*16 .. +15
        {
            int row = tid >> 2, prt = tid & 3;
            int tg = pt[m0 + row];
            float vals[16];
            float lm = -1e30f; int li = 0;
            #pragma unroll
            for (int c = 0; c < 16; c++) {
                int nc = n0 + prt * 16 + c;
                float x = (nc < V_) ? SCs[row][prt * 16 + c] : -1e30f;
                vals[c] = x;
                if (x > lm) { lm = x; li = nc; }
                if (nc == tg) rval[row] = x;
            }
            // combine max/argmax over the 4 parts (consecutive lanes, same wave)
            #pragma unroll
            for (int o = 1; o < 4; o <<= 1) {
                float om = __shfl_xor(lm, o, 64);
                int   oi = __shfl_xor(li, o, 64);
                if (om > lm || (om == lm && oi < li)) { lm = om; li = oi; }
            }
            float ls = 0.f;
            #pragma unroll
            for (int c = 0; c < 16; c++) {
                int nc = n0 + prt * 16 + c;
                if (nc < V_) ls += expf(vals[c] - lm);
            }
            #pragma unroll
            for (int o = 1; o < 4; o <<= 1) ls += __shfl_xor(ls, o, 64);
            if (prt == 0) {
                float om = rmax[row], os = rsum[row];
                float nm = fmaxf(om, lm);
                rsum[row] = os * expf(om - nm) + ls * expf(lm - nm);
                if (lm > om) rargi[row] = li;   // equal -> keep earlier (smaller n)
                rmax[row] = nm;
            }
        }
        __syncthreads();    // state settled before Bsf/SCs overwrite
    }

    // finalize rows -> block partials (tid 0..63 = wave 0)
    if (tid < 64) {
        int e = m0 + tid;
        int tg = pt[e];
        float pm = (float)dir[e];
        float lse = rmax[tid] + logf(rsum[tid]);
        float lloss = pm * (lse - rval[tid]);
        float lhit  = pm * ((rargi[tid] == tg) ? 1.f : 0.f);
        float lpm   = pm;
        lloss = wave_sum(lloss);
        lhit  = wave_sum(lhit);
        lpm   = wave_sum(lpm);
        if (tid == 0) {
            float* pr = part + (size_t)blockIdx.x * 8;
            pr[0] = lloss; pr[1] = lhit; pr[2] = lpm;
            pr[3] = 0.f; pr[4] = 0.f;
        }
    }
}

// ---------------- fused stop head (blocks 0..255) + root (blocks 256..511) ----------------

__global__ __launch_bounds__(256) void stoproot_k(const float* __restrict__ hbuf,
        const float* __restrict__ emb, const float* __restrict__ xtv,
        const int* __restrict__ wid, const int* __restrict__ noi, const float* __restrict__ now_w,
        const int* __restrict__ bidx, const int* __restrict__ dir,
        const int* __restrict__ rwid, const int* __restrict__ roi, const float* __restrict__ row_w,
        const float* __restrict__ wcls, const float* __restrict__ wbias,
        const float* __restrict__ ucls, const float* __restrict__ ubias,
        float* __restrict__ part) {
    __shared__ float red[256];
    __shared__ int   redi[256];
    __shared__ float shs[4];
    __shared__ float ctxs[L_];
    __shared__ float sc[V_];
    __shared__ float red2[4][2];

    if (blockIdx.x < 256) {
        // ---------- stop head per message (64 e's per block, wave-per-row) ----------
        int w = threadIdx.x >> 6, l = threadIdx.x & 63;
        int wg = blockIdx.x * 4 + w;

        float ua0[4], ub0[4], ua1[4], ub1[4], uc0[2], uc1[2];
        #pragma unroll
        for (int s = 0; s < 4; s++) {
            int j = s * 64 + l;
            ua0[s] = ucls[j];        ub0[s] = ucls[255 + j];
            ua1[s] = ucls[UD + j];   ub1[s] = ucls[UD + 255 + j];
        }
        #pragma unroll
        for (int s = 0; s < 2; s++) {
            int j = s * 64 + l;
            uc0[s] = ucls[510 + j];  uc1[s] = ucls[UD + 510 + j];
        }
        float u00 = ucls[0], u10 = ucls[UD];
        float ubs0 = ubias[0], ubs1 = ubias[1];

        float lloss = 0.f, lhit = 0.f;
        for (int i = 0; i < 16; i++) {
            int e = wg * 16 + i;
            const int*   ip = noi + e * K_;
            const float* wp = now_w + e * K_;
            float ave[4] = {0.f, 0.f, 0.f, 0.f};
            float wsum = 0.f;
            #pragma unroll
            for (int k = 0; k < K_; k++) {
                int id = ip[k]; float wt = wp[k];
                wsum += wt;
                const float* hr = hbuf + (size_t)id * H_;
                #pragma unroll
                for (int s = 0; s < 4; s++) ave[s] += wt * hr[s * 64 + l];
            }
            float inv = 1.f / fmaxf(wsum, 1e-8f);
            float innl = 0.f;
            #pragma unroll
            for (int s = 0; s < 4; s++) { ave[s] *= inv; innl += ave[s] * ave[s]; }
            if (l == 0) innl -= 2.f * ave[0] * ave[0];
            float inner = wave_sum(innl);
            float cs = 1.f / sqrtf(fmaxf(-inner, 1e-8f));

            int we = wid[e], bi = bidx[e];
            const float* er = emb + (size_t)we * H_;
            const float* cr = xtv + (size_t)bi * L_;

            float p0 = 0.f, p1 = 0.f;
            #pragma unroll
            for (int s = 0; s < 4; s++) {
                float cx = er[s * 64 + l];
                float co = ave[s] * cs;
                if (s == 0 && l == 0) {
                    float ctx0 = cr[0];
                    float t1sq = fmaxf(cx * cx + co * co - 1.f, 1e-8f);
                    float sh0 = sqrtf(fmaxf(t1sq + ctx0 * ctx0 - 1.f, 1e-8f));
                    p0 += -sh0 * u00; p1 += -sh0 * u10;
                } else {
                    p0 += cx * ua0[s] + co * ub0[s];
                    p1 += cx * ua1[s] + co * ub1[s];
                }
                if (s < 2) {
                    int j = s * 64 + l;
                    if (j >= 1) {
                        float ctx = cr[j];
                        p0 += ctx * uc0[s]; p1 += ctx * uc1[s];
                    }
                }
            }
            p0 = wave_sum(p0); p1 = wave_sum(p1);
            if (l == 0) {
                float sc0 = 2.f + 2.f * p0 + ubs0;
                float sc1 = 2.f + 2.f * p1 + ubs1;
                int tgt = dir[e];
                float mm = fmaxf(sc0, sc1);
                float lse = mm + logf(expf(sc0 - mm) + expf(sc1 - mm));
                lloss += lse - ((tgt == 0) ? sc0 : sc1);
                int am = (sc1 > sc0) ? 1 : 0;
                lhit += (am == tgt) ? 1.f : 0.f;
            }
        }
        if (l == 0) { red2[w][0] = lloss; red2[w][1] = lhit; }
        __syncthreads();
        if (threadIdx.x == 0) {
            float* pr = part + (size_t)(256 + blockIdx.x) * 8;
            pr[0] = 0.f; pr[1] = 0.f; pr[2] = 0.f;
            pr[3] = red2[0][0] + red2[1][0] + red2[2][0] + red2[3][0];
            pr[4] = red2[0][1] + red2[1][1] + red2[2][1] + red2[3][1];
        }
    } else {
        // ---------- root: stop head + pred head ----------
        int b = blockIdx.x - 256, j = threadIdx.x;
        float* pr = part + (size_t)(512 + b) * 8;

        const int*   ip = roi + b * K_;
        const float* wp = row_w + b * K_;
        float ave = 0.f, wsum = 0.f;
        #pragma unroll
        for (int k = 0; k < K_; k++) {
            int id = ip[k]; float w = wp[k];
            ave += w * hbuf[(size_t)id * H_ + j];
            wsum += w;
        }
        ave /= fmaxf(wsum, 1e-8f);
        float inner = blk_sum((j == 0) ? -ave * ave : ave * ave, red);
        float ro = ave / sqrtf(fmaxf(-inner, 1e-8f));

        int   rw = rwid[b];
        float er = emb[(size_t)rw * H_ + j];
        float ctxj = (j < L_) ? xtv[(size_t)b * L_ + j] : 0.f;
        if (j == 0) { shs[0] = er; shs[1] = ro; shs[2] = ctxj; }
        if (j < L_) ctxs[j] = ctxj;
        __syncthreads();
        float t1sq = fmaxf(shs[0] * shs[0] + shs[1] * shs[1] - 1.f, 1e-8f);
        float sh0  = sqrtf(fmaxf(t1sq + shs[2] * shs[2] - 1.f, 1e-8f));

        float p0, p1;
        if (j >= 1) {
            p0 = er * ucls[j] + ro * ucls[255 + j];
            p1 = er * ucls[UD + j] + ro * ucls[UD + 255 + j];
            if (j < L_) { p0 += ctxj * ucls[510 + j]; p1 += ctxj * ucls[UD + 510 + j]; }
        } else {
            p0 = -sh0 * ucls[0];
            p1 = -sh0 * ucls[UD];
        }
        float s0 = 2.f + 2.f * blk_sum(p0, red) + ubias[0];
        float s1 = 2.f + 2.f * blk_sum(p1, red) + ubias[1];
        if (j == 0) {
            float mm = fmaxf(s0, s1);
            float lse = mm + logf(expf(s0 - mm) + expf(s1 - mm));
            int am = (s1 > s0) ? 1 : 0;
            pr[3] = lse - s0;
            pr[4] = (am == 0) ? 1.f : 0.f;
        }

        float c0 = shs[2];
        float z0 = sqrtf(fmaxf(c0 * c0, 1e-8f));
        __syncthreads();
        for (int v = j; v < V_; v += 256) {
            const float* wv = wcls + (size_t)v * ZD;
            float d = -z0 * wv[0];
            for (int i = 1; i < L_; i++) d += ctxs[i] * wv[255 + i];
            sc[v] = 2.f + 2.f * d + wbias[v];
        }
        __syncthreads();
        float mx = -1e30f; int mi = 0;
        for (int v = j; v < V_; v += 256) { float x = sc[v]; if (x > mx) { mx = x; mi = v; } }
        red[j] = mx; redi[j] = mi;
        __syncthreads();
        for (int o = 128; o > 0; o >>= 1) {
            if (j < o) {
                float xo = red[j + o]; int io = redi[j + o];
                if (xo > red[j] || (xo == red[j] && io < redi[j])) { red[j] = xo; redi[j] = io; }
            }
            __syncthreads();
        }
        float gm = red[0]; int ga = redi[0];
        __syncthreads();
        float se = 0.f;
        for (int v = j; v < V_; v += 256) se += expf(sc[v] - gm);
        red[j] = se;
        __syncthreads();
        for (int o = 128; o > 0; o >>= 1) { if (j < o) red[j] += red[j + o]; __syncthreads(); }
        if (j == 0) {
            float lse = gm + logf(red[0]);
            pr[0] = lse - sc[rw];
            pr[1] = (ga == rw) ? 1.f : 0.f;
            pr[2] = 0.f;
        }
    }
}

// ---------------- finalize ----------------

__global__ __launch_bounds__(256) void finalize2(const float* __restrict__ part,
                                                 float* __restrict__ out) {
    int j = threadIdx.x;
    __shared__ float red[256][5];
    #pragma unroll
    for (int c = 0; c < 5; c++)
        red[j][c] = part[(size_t)j * 8 + c] + part[(size_t)(j + 256) * 8 + c]
                  + part[(size_t)(j + 512) * 8 + c];
    __syncthreads();
    for (int o = 128; o > 0; o >>= 1) {
        if (j < o) {
            #pragma unroll
            for (int c = 0; c < 5; c++) red[j][c] += red[j + o][c];
        }
        __syncthreads();
    }
    if (j == 0) {
        out[0] = red[0][0] / (float)B_;
        out[1] = red[0][3] / (float)B_;
        out[2] = red[0][1] / ((float)B_ + red[0][2]);
        out[3] = red[0][4] / (float)(E_ + B_);
    }
}

// ---------------- launch ----------------

extern "C" void kernel_launch(void* const* d_in, const int* in_sizes, int n_in,
                              void* d_out, int out_size, void* d_ws, size_t ws_size,
                              hipStream_t stream) {
    const int*   wid   = (const int*)d_in[0];
    const int*   nhi   = (const int*)d_in[1];
    const float* nhw   = (const float*)d_in[2];
    const int*   noi   = (const int*)d_in[3];
    const float* now_w = (const float*)d_in[4];
    const int*   bidx  = (const int*)d_in[5];
    const int*   dir   = (const int*)d_in[6];
    const int*   pt    = (const int*)d_in[7];
    const int*   rwid  = (const int*)d_in[8];
    const int*   roi   = (const int*)d_in[9];
    const float* row_w = (const float*)d_in[10];
    const float* xtv   = (const float*)d_in[11];
    const float* emb   = (const float*)d_in[12];
    const float* W0    = (const float*)d_in[13];
    const float* b0    = (const float*)d_in[14];
    const float* s0    = (const float*)d_in[15];
    const float* W1    = (const float*)d_in[16];
    const float* b1    = (const float*)d_in[17];
    const float* s1    = (const float*)d_in[18];
    const float* wcls  = (const float*)d_in[19];
    const float* wbias = (const float*)d_in[20];
    const float* ucls  = (const float*)d_in[21];
    const float* ubias = (const float*)d_in[22];

    float* ws   = (float*)d_ws;
    float* hbuf = ws;                                          // (E+1)*256 f32
    float* part = hbuf + (size_t)(E_ + 1) * H_;                // 768*8 f32
    _Float16* W0P = (_Float16*)(part + 768 * 8);               // 65536 fp16
    _Float16* W1P = W0P + 65536;                               // 131072 fp16
    _Float16* Zh  = W1P + 131072;                              // E*KP fp16
    _Float16* Wh  = Zh + (size_t)E_ * KP;                      // VP*KP fp16
    float* out  = (float*)d_out;

    prep_k<<<(PREP_TOTAL + 255) / 256, 256, 0, stream>>>(W0, W1, wcls, hbuf, W0P, W1P, Wh);

    scan_flow<<<M_, 256, 0, stream>>>(hbuf, W0P, b0, s0, W1P, b1, s1,
                                      emb, wid, nhi, nhw);

    zbuild2<<<E_, 256, 0, stream>>>(hbuf, xtv, bidx, Zh);
    gemm_ce<<<256, 256, 0, stream>>>(Zh, Wh, wbias, pt, dir, part);
    stoproot_k<<<512, 256, 0, stream>>>(hbuf, emb, xtv, wid, noi, now_w, bidx, dir,
                                        rwid, roi, row_w, wcls, wbias, ucls, ubias, part);
    finalize2<<<1, 256, 0, stream>>>(part, out);
}